// Round 13
// baseline (39.647 us; speedup 1.0000x reference)
//
#include <hip/hip_runtime.h>
#include <hip/hip_bf16.h>

// Chamfer loss via 32x32x16 MFMA — pre-packed records, single-stage main loop.
// predict_pc [B=4,3,N=8192] f32, gt_pc [B,3,N] f32.
// loss = sum_gt min_pred d / B + sum_pred min_gt d / B
//
// m := d^2/2 = on + qn - o.q via bf16 MFMA 32x32x16, split-bf16 (hi+lo ~fp32).
// Records (16 shorts, bit-identical to R6/R7/R10/R12-validated):
//   A (opposite): [-oh(3), -oh(3), -ol(3), -ol(3), onh, onl, 1, 1]
//   B (query):    [ qh(3),  ql(3),  qh(3),  ql(3), 1, 1, qnh, qnl]
// R12 post-mortem: main kernel ran at ~30% of the VALU-issue model; suspects
// were in-loop pack VALU + per-chunk barriers. This round: a tiny pack kernel
// precomputes all records in a HALF-SPLIT layout (per 32-rec group: 32
// lo-halves, then 32 hi-halves) so a 32x32 MFMA fragment read is exactly
// base + lane*16B (linear, conflict-free). Main kernel: stage the whole
// 32 KB opposite strip with 8 plain 16B copies/thread, ONE barrier, then 32
// uninterrupted i-steps {ds_read_b128 + 2 MFMA + min3 tree}. No in-loop
// packing, no chunk barriers, no prefetch scalars (R8/R11 spill trap gone).
// Output: strip-partial mins [2*4*NCS][N]; reduce1 min-merges + sqrt +
// block-sums; reduce2 sums. No atomics, no memset, deterministic.

#define NQ 256      // queries per block (4 waves x 2 frags x 32 cols)
#define JF 2        // B-frags per wave
#define NCS 8       // opposite-strip split count (strip = N/NCS = 1024)

typedef short short8 __attribute__((ext_vector_type(8)));
typedef float f32x16 __attribute__((ext_vector_type(16)));

static __device__ inline unsigned short f2bf(float f) {
    __hip_bfloat16 h = __float2bfloat16(f);
    return *reinterpret_cast<unsigned short*>(&h);
}
static __device__ inline float bf2f(unsigned short u) {
    __hip_bfloat16 h;
    *reinterpret_cast<unsigned short*>(&h) = u;
    return __bfloat162float(h);
}
static __device__ inline void split_bf(float v, unsigned short& hi,
                                       unsigned short& lo) {
    hi = f2bf(v);
    lo = f2bf(v - bf2f(hi));
}
static __device__ inline float min3f(float a, float b, float c) {
    return fminf(fminf(a, b), c);   // clang fuses to v_min3_f32
}

// Pack both record forms for every point of both sides, half-split layout:
// unit(rec n, half hf) lives at shorts[(n & ~31)*16 + hf*256 + (n&31)*8].
__global__ __launch_bounds__(256) void chamfer_pack_kernel(
    const float* __restrict__ pred, const float* __restrict__ gt,
    unsigned short* __restrict__ bufA, unsigned short* __restrict__ bufB,
    int N)
{
    int t = blockIdx.x * 256 + threadIdx.x;   // over 8*N points
    int n = t % N, sb = t / N;                // sb = side*4 + b (side1 = gt)
    const float* src = ((sb >> 2) ? gt : pred) + (size_t)(sb & 3) * 3 * N;
    float x = src[n], y = src[N + n], z = src[2 * N + n];

    unsigned short hx, lx, hy, ly, hz, lz, nh, nl;
    split_bf(x, hx, lx); split_bf(y, hy, ly); split_bf(z, hz, lz);
    float pn = 0.5f * fmaf(x, x, fmaf(y, y, z * z));
    split_bf(pn, nh, nl);
    const short ONE = 0x3F80;
    #define NG(u) ((short)((u) ^ 0x8000))
    short8 a0 = {NG(hx), NG(hy), NG(hz), NG(hx), NG(hy), NG(hz), NG(lx), NG(ly)};
    short8 a1 = {NG(lz), NG(lx), NG(ly), NG(lz), (short)nh, (short)nl, ONE, ONE};
    short8 b0 = {(short)hx, (short)hy, (short)hz, (short)lx, (short)ly,
                 (short)lz, (short)hx, (short)hy};
    short8 b1 = {(short)hz, (short)lx, (short)ly, (short)lz, ONE, ONE,
                 (short)nh, (short)nl};
    #undef NG

    size_t base = ((size_t)sb * N + (size_t)(n & ~31)) * 16;  // group base, shorts
    int li = (n & 31) * 8;
    *(short8*)(bufA + base + li)       = a0;   // lo half
    *(short8*)(bufA + base + 256 + li) = a1;   // hi half
    *(short8*)(bufB + base + li)       = b0;
    *(short8*)(bufB + base + 256 + li) = b1;
}

__global__ __launch_bounds__(256) void chamfer_mfma_kernel(
    const unsigned short* __restrict__ bufA,
    const unsigned short* __restrict__ bufB,
    float* __restrict__ partial,   // [(dir*4+b)*NCS+cs][N]
    int N, int qtiles)
{
    __align__(16) __shared__ unsigned short o_lds[2048 * 8];  // 32 KB

    int bid = blockIdx.x;
    int cs = bid % NCS;   int t1 = bid / NCS;
    int qt = t1 % qtiles; int t2 = t1 / qtiles;
    int b  = t2 & 3;      int dir = t2 >> 2;
    int sq = dir ? 0 : 1, so = 1 - sq;  // dir0: queries=gt(side1), opp=pred

    int tid = threadIdx.x;
    int lane = tid & 63, w = tid >> 6;
    int col = lane & 31, h = lane >> 5;
    int strip = N / NCS;   // 1024

    // ---- stage the whole opposite strip: 1024 recs = 2048 units of 16 B ----
    const unsigned short* abase =
        bufA + (((size_t)so * 4 + b) * N + (size_t)cs * strip) * 16;
    #pragma unroll
    for (int k = 0; k < 8; ++k) {
        int u = tid + k * 256;    // linear unit index: stream order == lane order
        *(short8*)&o_lds[u * 8] = *(const short8*)(abase + (size_t)u * 8);
    }

    // ---- B-frags: one 16 B global load each (half-split layout) ----
    const unsigned short* qgrp =
        bufB + (((size_t)sq * 4 + b) * N + (size_t)qt * NQ + w * 64) * 16;
    short8 bfrag[JF];
    #pragma unroll
    for (int j = 0; j < JF; ++j)
        bfrag[j] = *(const short8*)(qgrp + j * 512 + h * 256 + col * 8);
    __syncthreads();

    float mn[JF] = {3.0e38f, 3.0e38f};
    const f32x16 zero16 = {0.f};

    // ---- 32 uninterrupted i-steps: ds_read_b128 + 2 MFMA + min3 trees ----
    #pragma unroll 4
    for (int i = 0; i < strip / 32; ++i) {
        short8 af = *(const short8*)&o_lds[i * 512 + lane * 8];
        #pragma unroll
        for (int j = 0; j < JF; ++j) {
            f32x16 acc = __builtin_amdgcn_mfma_f32_32x32x16_bf16(
                af, bfrag[j], zero16, 0, 0, 0);
            float l0 = min3f(acc[0],  acc[1],  acc[2]);
            float l1 = min3f(acc[3],  acc[4],  acc[5]);
            float l2 = min3f(acc[6],  acc[7],  acc[8]);
            float l3 = min3f(acc[9],  acc[10], acc[11]);
            float l4 = min3f(acc[12], acc[13], acc[14]);
            float m0 = min3f(l0, l1, l2);
            float m1 = min3f(l3, l4, acc[15]);
            mn[j] = min3f(m0, m1, mn[j]);
        }
    }

    // fold the two k-half lane groups (rows +4h) of each query column
    #pragma unroll
    for (int j = 0; j < JF; ++j)
        mn[j] = fminf(mn[j], __shfl_xor(mn[j], 32, 64));

    if (lane < 32) {
        float* pp = partial + ((size_t)((dir * 4 + b) * NCS + cs)) * N
                  + qt * NQ + w * 64 + col;
        #pragma unroll
        for (int j = 0; j < JF; ++j) pp[j * 32] = mn[j];
    }
}

__global__ __launch_bounds__(256) void chamfer_reduce1_kernel(
    const float* __restrict__ partial, float* __restrict__ partials2, int N)
{
    __shared__ float sdata[256];
    int L = blockIdx.x * 256 + threadIdx.x;   // over 2*B*N queries
    int dirb = L / N, q = L - dirb * N;
    const float* pp = partial + (size_t)dirb * NCS * N + q;
    float v = pp[0];
    #pragma unroll
    for (int cs = 1; cs < NCS; ++cs) v = fminf(v, pp[(size_t)cs * N]);
    float s = sqrtf(fmaxf(2.0f * v, 0.0f));   // d = sqrt(2m)
    sdata[threadIdx.x] = s;
    __syncthreads();
    for (int off = 128; off > 0; off >>= 1) {
        if (threadIdx.x < off) sdata[threadIdx.x] += sdata[threadIdx.x + off];
        __syncthreads();
    }
    if (threadIdx.x == 0) partials2[blockIdx.x] = sdata[0];
}

__global__ __launch_bounds__(256) void chamfer_reduce2_kernel(
    const float* __restrict__ partials2, float* __restrict__ out, float inv_b)
{
    __shared__ float sdata[256];
    sdata[threadIdx.x] = partials2[threadIdx.x];
    __syncthreads();
    for (int off = 128; off > 0; off >>= 1) {
        if (threadIdx.x < off) sdata[threadIdx.x] += sdata[threadIdx.x + off];
        __syncthreads();
    }
    if (threadIdx.x == 0) out[0] = sdata[0] * inv_b;
}

extern "C" void kernel_launch(void* const* d_in, const int* in_sizes, int n_in,
                              void* d_out, int out_size, void* d_ws, size_t ws_size,
                              hipStream_t stream) {
    const float* pred = (const float*)d_in[0];
    const float* gt   = (const float*)d_in[1];
    const int B = 4, D = 3;
    const int N = in_sizes[0] / (B * D);   // 8192

    // ws: bufA (8N recs * 32 B = 4 MB) | bufB (4 MB) | partial 2 MB | partials2
    unsigned short* bufA = (unsigned short*)d_ws;
    unsigned short* bufB = bufA + (size_t)8 * N * 16;
    float* partial   = (float*)(bufB + (size_t)8 * N * 16);  // [2*B*NCS][N]
    float* partials2 = partial + (size_t)2 * B * NCS * N;    // [256]

    chamfer_pack_kernel<<<dim3(8 * N / 256), dim3(256), 0, stream>>>(
        pred, gt, bufA, bufB, N);

    int qtiles = N / NQ;               // 32
    dim3 grid1(2 * B * qtiles * NCS);  // 2048 blocks
    chamfer_mfma_kernel<<<grid1, dim3(256), 0, stream>>>(
        bufA, bufB, partial, N, qtiles);

    chamfer_reduce1_kernel<<<dim3(2 * B * N / 256), dim3(256), 0, stream>>>(
        partial, partials2, N);
    chamfer_reduce2_kernel<<<dim3(1), dim3(256), 0, stream>>>(
        partials2, (float*)d_out, 1.0f / B);
}